// Round 3
// baseline (1685.798 us; speedup 1.0000x reference)
//
#include <hip/hip_runtime.h>
#include <hip/hip_fp16.h>

#define N_NODES 100000
#define N_EDGES 1600000
#define IN_F 128
#define OUT_F 32
#define HEADS 2
#define HO 64  // HEADS*OUT_F

#define SCAN_TILE 2048
#define NB_SCAN ((N_NODES + SCAN_TILE - 1) / SCAN_TILE)  // 49

__global__ void init_ws_k(int* __restrict__ deg, int* __restrict__ cursor){
  int i = blockIdx.x*blockDim.x + threadIdx.x;
  if (i < N_NODES){ deg[i] = 0; cursor[i] = 0; }
}

// feat = x @ W (N x 128 @ 128 x 64) -> fp16, fused el/er.
// Block 256 = 4 waves; block handles 64 nodes in 4 groups of 16; wave handles 4 nodes at once.
// W transposed into LDS Wt[col][k] with row stride 132 (float4-friendly, conflict-free).
__global__ void feat_k(const float* __restrict__ x, const float* __restrict__ W,
                       const float* __restrict__ attn_l, const float* __restrict__ attn_r,
                       __half* __restrict__ feat16, float* __restrict__ el, float* __restrict__ er){
  __shared__ __align__(16) float Wt[64*132];   // 33.8 KB
  __shared__ __align__(16) float xs[16*128];   // 8 KB
  int tid = threadIdx.x;
  for (int i = tid; i < IN_F*HO; i += 256){
    int k = i >> 6, c = i & 63;
    Wt[c*132 + k] = W[i];
  }
  int w = tid >> 6, lane = tid & 63;
  float al = attn_l[lane], ar = attn_r[lane];
  int nb = w*4;
  for (int g = 0; g < 4; ++g){
    int node0 = blockIdx.x*64 + g*16;
    __syncthreads();
    for (int i = tid; i < 16*32; i += 256){     // float4 granularity
      int ln = i >> 5, kq = i & 31;
      int n = node0 + ln;
      float4 v = (n < N_NODES) ? ((const float4*)x)[(size_t)n*32 + kq] : make_float4(0.f,0.f,0.f,0.f);
      ((float4*)xs)[ln*32 + kq] = v;
    }
    __syncthreads();
    float acc[4] = {0.f,0.f,0.f,0.f};
    for (int k = 0; k < IN_F; k += 4){
      float4 wv = *(const float4*)&Wt[lane*132 + k];
      #pragma unroll
      for (int j = 0; j < 4; ++j){
        float4 xv = *(const float4*)&xs[(nb+j)*128 + k];
        acc[j] = fmaf(xv.x, wv.x, acc[j]);
        acc[j] = fmaf(xv.y, wv.y, acc[j]);
        acc[j] = fmaf(xv.z, wv.z, acc[j]);
        acc[j] = fmaf(xv.w, wv.w, acc[j]);
      }
    }
    #pragma unroll
    for (int j = 0; j < 4; ++j){
      int n = node0 + nb + j;
      float a = acc[j];
      float p = a*al, q = a*ar;
      #pragma unroll
      for (int off = 16; off; off >>= 1){ p += __shfl_xor(p, off); q += __shfl_xor(q, off); }
      if (n < N_NODES){
        feat16[(size_t)n*HO + lane] = __float2half(a);
        if ((lane & 31) == 0){ el[n*HEADS + (lane>>5)] = p; er[n*HEADS + (lane>>5)] = q; }
      }
    }
  }
}

__global__ void fold_w_k(const float* __restrict__ W1, const float* __restrict__ b1,
                         const float* __restrict__ W2, const float* __restrict__ b2,
                         float* __restrict__ wcomb, float* __restrict__ ccomb){
  int j = threadIdx.x;
  if (j < HO){
    float a = 0.f;
    for (int t = 0; t < OUT_F; ++t) a = fmaf(W1[j*OUT_F + t], W2[t], a);
    wcomb[j] = a;
  }
  if (j == HO){
    float a = 0.f;
    for (int t = 0; t < OUT_F; ++t) a = fmaf(b1[t], W2[t], a);
    *ccomb = a + b2[0];
  }
}

__global__ void hist_k(const int* __restrict__ dst, int* __restrict__ deg){
  int e = blockIdx.x*blockDim.x + threadIdx.x;
  if (e < N_EDGES) atomicAdd(&deg[dst[e]], 1);
}

__global__ void scan1_k(const int* __restrict__ deg, int* __restrict__ exsc, int* __restrict__ tsum){
  __shared__ int sh[256];
  int b = blockIdx.x, t = threadIdx.x;
  int base = b*SCAN_TILE + t*8;
  int v[8]; int local = 0;
  #pragma unroll
  for (int i = 0; i < 8; ++i){
    int idx = base + i;
    v[i] = (idx < N_NODES) ? deg[idx] : 0;
    local += v[i];
  }
  sh[t] = local; __syncthreads();
  for (int off = 1; off < 256; off <<= 1){
    int xv = (t >= off) ? sh[t-off] : 0;
    __syncthreads();
    sh[t] += xv;
    __syncthreads();
  }
  int run = sh[t] - local;
  if (t == 255) tsum[b] = sh[255];
  #pragma unroll
  for (int i = 0; i < 8; ++i){
    int idx = base + i;
    if (idx < N_NODES) exsc[idx] = run;
    run += v[i];
  }
}

__global__ void scan2_k(const int* __restrict__ tsum, int* __restrict__ toff){
  __shared__ int sh[64];
  int t = threadIdx.x;
  int v = (t < NB_SCAN) ? tsum[t] : 0;
  sh[t] = v; __syncthreads();
  for (int off = 1; off < 64; off <<= 1){
    int xv = (t >= off) ? sh[t-off] : 0;
    __syncthreads();
    sh[t] += xv;
    __syncthreads();
  }
  if (t < NB_SCAN) toff[t] = sh[t] - v;
}

__global__ void scan3_k(const int* __restrict__ exsc, const int* __restrict__ toff,
                        int* __restrict__ rowptr){
  int b = blockIdx.x, t = threadIdx.x;
  int base = b*SCAN_TILE + t*8;
  int add = toff[b];
  #pragma unroll
  for (int i = 0; i < 8; ++i){
    int idx = base + i;
    if (idx < N_NODES) rowptr[idx] = exsc[idx] + add;
  }
  if (b == 0 && t == 0) rowptr[N_NODES] = N_EDGES;
}

// CSR-by-dst scatter, src index only (4B payload)
__global__ void scatter_k(const int* __restrict__ src, const int* __restrict__ dst,
                          const int* __restrict__ rowptr, int* __restrict__ cursor,
                          int* __restrict__ srcs){
  int e = blockIdx.x*blockDim.x + threadIdx.x;
  if (e >= N_EDGES) return;
  int d = dst[e];
  int pos = atomicAdd(&cursor[d], 1);
  srcs[rowptr[d] + pos] = src[e];
}

// One wave per dst node. Pass1: gather logits (cached in regs), max. Pass2: sum exp.
// Pass3: 4-edge groups (16 lanes x 8B fp16 = 128B row each), fp32 accumulate.
// Fused epilogue: bias + head-mean + relu + folded-MLP dot.
__global__ void node_agg_k(const int* __restrict__ rowptr, const int* __restrict__ srcs,
                           const float* __restrict__ el, const float* __restrict__ er,
                           const __half* __restrict__ feat16, const float* __restrict__ bias,
                           const float* __restrict__ wcomb,
                           float* __restrict__ s1, float* __restrict__ s2){
  int wid = (blockIdx.x*blockDim.x + threadIdx.x) >> 6;
  if (wid >= N_NODES) return;
  int lane = threadIdx.x & 63;
  int b = rowptr[wid];
  int cnt = rowptr[wid+1] - b;
  float er0 = er[wid*HEADS + 0], er1 = er[wid*HEADS + 1];

  // pass 1: gather + register-cache logits, per-head max
  float t0c[4], t1c[4];
  float m0 = -1e30f, m1 = -1e30f;
  int slots = (cnt + 63) >> 6;
  for (int s = 0; s < slots; ++s){
    int jj = s*64 + lane;
    float t0 = -1e30f, t1 = -1e30f;
    if (jj < cnt){
      int sn = srcs[b + jj];
      float e0 = el[sn*HEADS + 0] + er0;
      float e1 = el[sn*HEADS + 1] + er1;
      t0 = e0 > 0.f ? e0 : 0.2f*e0;
      t1 = e1 > 0.f ? e1 : 0.2f*e1;
    }
    if (s < 4){ t0c[s] = t0; t1c[s] = t1; }
    m0 = fmaxf(m0, t0); m1 = fmaxf(m1, t1);
  }
  #pragma unroll
  for (int off = 32; off; off >>= 1){
    m0 = fmaxf(m0, __shfl_xor(m0, off));
    m1 = fmaxf(m1, __shfl_xor(m1, off));
  }

  // pass 2: sum of exp (from register cache; regather in the astronomically-rare deg>256 case)
  float sum0 = 0.f, sum1 = 0.f;
  for (int s = 0; s < slots; ++s){
    float t0, t1;
    if (s < 4){ t0 = t0c[s]; t1 = t1c[s]; }
    else {
      int jj = s*64 + lane;
      t0 = -1e30f; t1 = -1e30f;
      if (jj < cnt){
        int sn = srcs[b + jj];
        float e0 = el[sn*HEADS + 0] + er0;
        float e1 = el[sn*HEADS + 1] + er1;
        t0 = e0 > 0.f ? e0 : 0.2f*e0;
        t1 = e1 > 0.f ? e1 : 0.2f*e1;
      }
    }
    sum0 += __expf(t0 - m0);
    sum1 += __expf(t1 - m1);
  }
  #pragma unroll
  for (int off = 32; off; off >>= 1){
    sum0 += __shfl_xor(sum0, off);
    sum1 += __shfl_xor(sum1, off);
  }
  float r0 = sum0 > 0.f ? 1.f/sum0 : 0.f;
  float r1 = sum1 > 0.f ? 1.f/sum1 : 0.f;

  // pass 3: 4 edges in flight; lane = (g<<4)|c4; cols 4*c4..4*c4+3
  int g  = lane >> 4;
  int c4 = lane & 15;
  int h  = (c4 >= 8);
  float mh = h ? m1 : m0;
  float rh = h ? r1 : r0;
  float erh = h ? er1 : er0;
  float a0=0.f, a1=0.f, a2=0.f, a3=0.f;
  for (int j0 = 0; j0 < cnt; j0 += 4){
    int jj = j0 + g;
    float alpha = 0.f;
    int sn = 0;
    if (jj < cnt){
      sn = srcs[b + jj];
      float e = el[sn*HEADS + h] + erh;
      float t = e > 0.f ? e : 0.2f*e;
      alpha = __expf(t - mh) * rh;
    }
    uint2 v = *(const uint2*)(feat16 + (size_t)sn*HO + c4*4);
    float2 f01 = __half22float2(*(const __half2*)&v.x);
    float2 f23 = __half22float2(*(const __half2*)&v.y);
    a0 = fmaf(alpha, f01.x, a0);
    a1 = fmaf(alpha, f01.y, a1);
    a2 = fmaf(alpha, f23.x, a2);
    a3 = fmaf(alpha, f23.y, a3);
  }
  // combine the 4 edge-groups
  a0 += __shfl_xor(a0, 16); a1 += __shfl_xor(a1, 16); a2 += __shfl_xor(a2, 16); a3 += __shfl_xor(a3, 16);
  a0 += __shfl_xor(a0, 32); a1 += __shfl_xor(a1, 32); a2 += __shfl_xor(a2, 32); a3 += __shfl_xor(a3, 32);
  // bias
  a0 += bias[c4*4 + 0]; a1 += bias[c4*4 + 1]; a2 += bias[c4*4 + 2]; a3 += bias[c4*4 + 3];
  // head mean (pair c4 with c4^8) + relu
  float h0 = 0.5f*(a0 + __shfl_xor(a0, 8)); h0 = fmaxf(h0, 0.f);
  float h1 = 0.5f*(a1 + __shfl_xor(a1, 8)); h1 = fmaxf(h1, 0.f);
  float h2 = 0.5f*(a2 + __shfl_xor(a2, 8)); h2 = fmaxf(h2, 0.f);
  float h3 = 0.5f*(a3 + __shfl_xor(a3, 8)); h3 = fmaxf(h3, 0.f);
  int f0 = (c4 & 7)*4;
  float p = h0*wcomb[f0] + h1*wcomb[f0+1] + h2*wcomb[f0+2] + h3*wcomb[f0+3];
  float q = h0*wcomb[32+f0] + h1*wcomb[32+f0+1] + h2*wcomb[32+f0+2] + h3*wcomb[32+f0+3];
  #pragma unroll
  for (int off = 4; off; off >>= 1){
    p += __shfl_xor(p, off);
    q += __shfl_xor(q, off);
  }
  if (lane == 0){ s1[wid] = p; s2[wid] = q; }
}

__global__ void edge_score_k(const int* __restrict__ src, const int* __restrict__ dst,
                             const float* __restrict__ s1, const float* __restrict__ s2,
                             const float* __restrict__ ccomb, float* __restrict__ out){
  int e = blockIdx.x*blockDim.x + threadIdx.x;
  if (e >= N_EDGES) return;
  out[e] = s1[src[e]] + s2[dst[e]] + ccomb[0];
}

extern "C" void kernel_launch(void* const* d_in, const int* in_sizes, int n_in,
                              void* d_out, int out_size, void* d_ws, size_t ws_size,
                              hipStream_t stream){
  const float* x      = (const float*)d_in[0];
  const float* W      = (const float*)d_in[1];
  const float* attn_l = (const float*)d_in[2];
  const float* attn_r = (const float*)d_in[3];
  const float* bias   = (const float*)d_in[4];
  const float* W1     = (const float*)d_in[5];
  const float* b1     = (const float*)d_in[6];
  const float* W2     = (const float*)d_in[7];
  const float* b2     = (const float*)d_in[8];
  const int*   src    = (const int*)d_in[9];
  const int*   dst    = (const int*)d_in[10];
  float* out = (float*)d_out;

  float* ws = (float*)d_ws;
  size_t off = 0;
  __half* feat16 = (__half*)(ws + off); off += (size_t)N_NODES*HO/2;  // 12.8 MB as halfs
  float*  el     = ws + off; off += (size_t)N_NODES*HEADS;
  float*  er     = ws + off; off += (size_t)N_NODES*HEADS;
  float*  s1     = ws + off; off += N_NODES;
  float*  s2     = ws + off; off += N_NODES;
  float*  wcomb  = ws + off; off += 64;
  float*  ccomb  = ws + off; off += 64;
  int*    deg    = (int*)(ws + off); off += N_NODES;
  int*    cursor = (int*)(ws + off); off += N_NODES;
  int*    exsc   = (int*)(ws + off); off += N_NODES;
  int*    rowptr = (int*)(ws + off); off += N_NODES + 1;
  int*    tsum   = (int*)(ws + off); off += NB_SCAN;
  int*    toff   = (int*)(ws + off); off += NB_SCAN + 2;
  int*    srcs   = (int*)(ws + off); off += N_EDGES;

  init_ws_k<<<(N_NODES + 255)/256, 256, 0, stream>>>(deg, cursor);
  feat_k<<<(N_NODES + 63)/64, 256, 0, stream>>>(x, W, attn_l, attn_r, feat16, el, er);
  fold_w_k<<<1, 128, 0, stream>>>(W1, b1, W2, b2, wcomb, ccomb);
  hist_k<<<(N_EDGES + 255)/256, 256, 0, stream>>>(dst, deg);
  scan1_k<<<NB_SCAN, 256, 0, stream>>>(deg, exsc, tsum);
  scan2_k<<<1, 64, 0, stream>>>(tsum, toff);
  scan3_k<<<NB_SCAN, 256, 0, stream>>>(exsc, toff, rowptr);
  scatter_k<<<(N_EDGES + 255)/256, 256, 0, stream>>>(src, dst, rowptr, cursor, srcs);
  node_agg_k<<<((size_t)N_NODES*64 + 255)/256, 256, 0, stream>>>(rowptr, srcs, el, er, feat16, bias, wcomb, s1, s2);
  edge_score_k<<<(N_EDGES + 255)/256, 256, 0, stream>>>(src, dst, s1, s2, ccomb, out);
}

// Round 4
// 432.506 us; speedup vs baseline: 3.8977x; 3.8977x over previous
//
#include <hip/hip_runtime.h>
#include <hip/hip_fp16.h>

#define N_NODES 100000
#define N_EDGES 1600000
#define IN_F 128
#define OUT_F 32
#define HEADS 2
#define HO 64  // HEADS*OUT_F

#define SCAN_TILE 2048
#define NB_SCAN ((N_NODES + SCAN_TILE - 1) / SCAN_TILE)  // 49

__global__ void init_ws_k(int* __restrict__ deg, int* __restrict__ cursor){
  int i = blockIdx.x*blockDim.x + threadIdx.x;
  if (i < N_NODES){ deg[i] = 0; cursor[i] = 0; }
}

// feat = x @ W (N x 128 @ 128 x 64) -> fp16, fused el/er.
// Block 256 threads = 64-node tile. Thread (nq,cq) computes a 4-node x 4-col tile.
// LDS: Ws natural [128][64] (float4 reads at 4*cq -> 2-way bank alias = free),
//      xs row-major [64][132] (pad 132: 4*nq*132 mod 32 in {0,16} -> 2-way = free).
// Hot loop: 8 ds_read_b128 per 4-k step feeding 64 FMAs (8:1), VALU-bound.
__global__ void feat_k(const float* __restrict__ x, const float* __restrict__ W,
                       const float* __restrict__ attn_l, const float* __restrict__ attn_r,
                       __half* __restrict__ feat16, float* __restrict__ el, float* __restrict__ er){
  __shared__ __align__(16) float Ws[IN_F*HO];   // 32 KB
  __shared__ __align__(16) float xs[64*132];    // 33.8 KB
  int tid = threadIdx.x;
  int node0 = blockIdx.x*64;
  // stage W: straight coalesced float4 copy
  for (int i = tid; i < 2048; i += 256)
    ((float4*)Ws)[i] = ((const float4*)W)[i];
  // stage x tile: coalesced float4 row copy into padded rows
  for (int i = tid; i < 2048; i += 256){
    int ln = i >> 5, kq = i & 31;
    int n = node0 + ln;
    float4 v = (n < N_NODES) ? ((const float4*)x)[(size_t)n*32 + kq]
                             : make_float4(0.f,0.f,0.f,0.f);
    *(float4*)&xs[ln*132 + kq*4] = v;
  }
  __syncthreads();

  int nq = tid >> 4;        // 0..15
  int cq = tid & 15;        // 0..15
  int n0 = nq*4, c0 = cq*4;
  float acc[4][4] = {{0.f,0.f,0.f,0.f},{0.f,0.f,0.f,0.f},{0.f,0.f,0.f,0.f},{0.f,0.f,0.f,0.f}};

  for (int k = 0; k < IN_F; k += 4){
    float xk[4][4];
    #pragma unroll
    for (int j = 0; j < 4; ++j){
      float4 t = *(const float4*)&xs[(n0+j)*132 + k];
      xk[j][0]=t.x; xk[j][1]=t.y; xk[j][2]=t.z; xk[j][3]=t.w;
    }
    #pragma unroll
    for (int d = 0; d < 4; ++d){
      float4 w4 = *(const float4*)&Ws[(k+d)*HO + c0];
      #pragma unroll
      for (int j = 0; j < 4; ++j){
        acc[j][0] = fmaf(xk[j][d], w4.x, acc[j][0]);
        acc[j][1] = fmaf(xk[j][d], w4.y, acc[j][1]);
        acc[j][2] = fmaf(xk[j][d], w4.z, acc[j][2]);
        acc[j][3] = fmaf(xk[j][d], w4.w, acc[j][3]);
      }
    }
  }

  // epilogue: partial el/er dot over this thread's 4 cols, reduce over cq octet
  float4 al4 = *(const float4*)&attn_l[c0];
  float4 ar4 = *(const float4*)&attn_r[c0];
  #pragma unroll
  for (int j = 0; j < 4; ++j){
    int n = node0 + n0 + j;
    float p = acc[j][0]*al4.x + acc[j][1]*al4.y + acc[j][2]*al4.z + acc[j][3]*al4.w;
    float q = acc[j][0]*ar4.x + acc[j][1]*ar4.y + acc[j][2]*ar4.z + acc[j][3]*ar4.w;
    #pragma unroll
    for (int off = 4; off; off >>= 1){ p += __shfl_xor(p, off); q += __shfl_xor(q, off); }
    if (n < N_NODES){
      __half2 h01 = __float22half2_rn(make_float2(acc[j][0], acc[j][1]));
      __half2 h23 = __float22half2_rn(make_float2(acc[j][2], acc[j][3]));
      union { uint2 u; __half2 h[2]; } pk; pk.h[0]=h01; pk.h[1]=h23;
      *(uint2*)&feat16[(size_t)n*HO + c0] = pk.u;
      if ((cq & 7) == 0){
        int h = cq >> 3;
        el[n*HEADS + h] = p;
        er[n*HEADS + h] = q;
      }
    }
  }
}

__global__ void fold_w_k(const float* __restrict__ W1, const float* __restrict__ b1,
                         const float* __restrict__ W2, const float* __restrict__ b2,
                         float* __restrict__ wcomb, float* __restrict__ ccomb){
  int j = threadIdx.x;
  if (j < HO){
    float a = 0.f;
    for (int t = 0; t < OUT_F; ++t) a = fmaf(W1[j*OUT_F + t], W2[t], a);
    wcomb[j] = a;
  }
  if (j == HO){
    float a = 0.f;
    for (int t = 0; t < OUT_F; ++t) a = fmaf(b1[t], W2[t], a);
    *ccomb = a + b2[0];
  }
}

__global__ void hist_k(const int* __restrict__ dst, int* __restrict__ deg){
  int e = blockIdx.x*blockDim.x + threadIdx.x;
  if (e < N_EDGES) atomicAdd(&deg[dst[e]], 1);
}

__global__ void scan1_k(const int* __restrict__ deg, int* __restrict__ exsc, int* __restrict__ tsum){
  __shared__ int sh[256];
  int b = blockIdx.x, t = threadIdx.x;
  int base = b*SCAN_TILE + t*8;
  int v[8]; int local = 0;
  #pragma unroll
  for (int i = 0; i < 8; ++i){
    int idx = base + i;
    v[i] = (idx < N_NODES) ? deg[idx] : 0;
    local += v[i];
  }
  sh[t] = local; __syncthreads();
  for (int off = 1; off < 256; off <<= 1){
    int xv = (t >= off) ? sh[t-off] : 0;
    __syncthreads();
    sh[t] += xv;
    __syncthreads();
  }
  int run = sh[t] - local;
  if (t == 255) tsum[b] = sh[255];
  #pragma unroll
  for (int i = 0; i < 8; ++i){
    int idx = base + i;
    if (idx < N_NODES) exsc[idx] = run;
    run += v[i];
  }
}

__global__ void scan2_k(const int* __restrict__ tsum, int* __restrict__ toff){
  __shared__ int sh[64];
  int t = threadIdx.x;
  int v = (t < NB_SCAN) ? tsum[t] : 0;
  sh[t] = v; __syncthreads();
  for (int off = 1; off < 64; off <<= 1){
    int xv = (t >= off) ? sh[t-off] : 0;
    __syncthreads();
    sh[t] += xv;
    __syncthreads();
  }
  if (t < NB_SCAN) toff[t] = sh[t] - v;
}

__global__ void scan3_k(const int* __restrict__ exsc, const int* __restrict__ toff,
                        int* __restrict__ rowptr){
  int b = blockIdx.x, t = threadIdx.x;
  int base = b*SCAN_TILE + t*8;
  int add = toff[b];
  #pragma unroll
  for (int i = 0; i < 8; ++i){
    int idx = base + i;
    if (idx < N_NODES) rowptr[idx] = exsc[idx] + add;
  }
  if (b == 0 && t == 0) rowptr[N_NODES] = N_EDGES;
}

// CSR-by-dst scatter, src index only (4B payload)
__global__ void scatter_k(const int* __restrict__ src, const int* __restrict__ dst,
                          const int* __restrict__ rowptr, int* __restrict__ cursor,
                          int* __restrict__ srcs){
  int e = blockIdx.x*blockDim.x + threadIdx.x;
  if (e >= N_EDGES) return;
  int d = dst[e];
  int pos = atomicAdd(&cursor[d], 1);
  srcs[rowptr[d] + pos] = src[e];
}

// One wave per dst node. Pass1: gather logits (cached in regs), max. Pass2: sum exp.
// Pass3: 4-edge groups (16 lanes x 8B fp16 = 128B row each), fp32 accumulate.
// Fused epilogue: bias + head-mean + relu + folded-MLP dot.
__global__ void node_agg_k(const int* __restrict__ rowptr, const int* __restrict__ srcs,
                           const float* __restrict__ el, const float* __restrict__ er,
                           const __half* __restrict__ feat16, const float* __restrict__ bias,
                           const float* __restrict__ wcomb,
                           float* __restrict__ s1, float* __restrict__ s2){
  int wid = (blockIdx.x*blockDim.x + threadIdx.x) >> 6;
  if (wid >= N_NODES) return;
  int lane = threadIdx.x & 63;
  int b = rowptr[wid];
  int cnt = rowptr[wid+1] - b;
  float er0 = er[wid*HEADS + 0], er1 = er[wid*HEADS + 1];

  float t0c[4], t1c[4];
  float m0 = -1e30f, m1 = -1e30f;
  int slots = (cnt + 63) >> 6;
  for (int s = 0; s < slots; ++s){
    int jj = s*64 + lane;
    float t0 = -1e30f, t1 = -1e30f;
    if (jj < cnt){
      int sn = srcs[b + jj];
      float e0 = el[sn*HEADS + 0] + er0;
      float e1 = el[sn*HEADS + 1] + er1;
      t0 = e0 > 0.f ? e0 : 0.2f*e0;
      t1 = e1 > 0.f ? e1 : 0.2f*e1;
    }
    if (s < 4){ t0c[s] = t0; t1c[s] = t1; }
    m0 = fmaxf(m0, t0); m1 = fmaxf(m1, t1);
  }
  #pragma unroll
  for (int off = 32; off; off >>= 1){
    m0 = fmaxf(m0, __shfl_xor(m0, off));
    m1 = fmaxf(m1, __shfl_xor(m1, off));
  }

  float sum0 = 0.f, sum1 = 0.f;
  for (int s = 0; s < slots; ++s){
    float t0, t1;
    if (s < 4){ t0 = t0c[s]; t1 = t1c[s]; }
    else {
      int jj = s*64 + lane;
      t0 = -1e30f; t1 = -1e30f;
      if (jj < cnt){
        int sn = srcs[b + jj];
        float e0 = el[sn*HEADS + 0] + er0;
        float e1 = el[sn*HEADS + 1] + er1;
        t0 = e0 > 0.f ? e0 : 0.2f*e0;
        t1 = e1 > 0.f ? e1 : 0.2f*e1;
      }
    }
    sum0 += __expf(t0 - m0);
    sum1 += __expf(t1 - m1);
  }
  #pragma unroll
  for (int off = 32; off; off >>= 1){
    sum0 += __shfl_xor(sum0, off);
    sum1 += __shfl_xor(sum1, off);
  }
  float r0 = sum0 > 0.f ? 1.f/sum0 : 0.f;
  float r1 = sum1 > 0.f ? 1.f/sum1 : 0.f;

  int g  = lane >> 4;
  int c4 = lane & 15;
  int h  = (c4 >= 8);
  float mh = h ? m1 : m0;
  float rh = h ? r1 : r0;
  float erh = h ? er1 : er0;
  float a0=0.f, a1=0.f, a2=0.f, a3=0.f;
  for (int j0 = 0; j0 < cnt; j0 += 4){
    int jj = j0 + g;
    float alpha = 0.f;
    int sn = 0;
    if (jj < cnt){
      sn = srcs[b + jj];
      float e = el[sn*HEADS + h] + erh;
      float t = e > 0.f ? e : 0.2f*e;
      alpha = __expf(t - mh) * rh;
    }
    uint2 v = *(const uint2*)(feat16 + (size_t)sn*HO + c4*4);
    float2 f01 = __half22float2(*(const __half2*)&v.x);
    float2 f23 = __half22float2(*(const __half2*)&v.y);
    a0 = fmaf(alpha, f01.x, a0);
    a1 = fmaf(alpha, f01.y, a1);
    a2 = fmaf(alpha, f23.x, a2);
    a3 = fmaf(alpha, f23.y, a3);
  }
  a0 += __shfl_xor(a0, 16); a1 += __shfl_xor(a1, 16); a2 += __shfl_xor(a2, 16); a3 += __shfl_xor(a3, 16);
  a0 += __shfl_xor(a0, 32); a1 += __shfl_xor(a1, 32); a2 += __shfl_xor(a2, 32); a3 += __shfl_xor(a3, 32);
  a0 += bias[c4*4 + 0]; a1 += bias[c4*4 + 1]; a2 += bias[c4*4 + 2]; a3 += bias[c4*4 + 3];
  float h0 = 0.5f*(a0 + __shfl_xor(a0, 8)); h0 = fmaxf(h0, 0.f);
  float h1 = 0.5f*(a1 + __shfl_xor(a1, 8)); h1 = fmaxf(h1, 0.f);
  float h2 = 0.5f*(a2 + __shfl_xor(a2, 8)); h2 = fmaxf(h2, 0.f);
  float h3 = 0.5f*(a3 + __shfl_xor(a3, 8)); h3 = fmaxf(h3, 0.f);
  int f0 = (c4 & 7)*4;
  float p = h0*wcomb[f0] + h1*wcomb[f0+1] + h2*wcomb[f0+2] + h3*wcomb[f0+3];
  float q = h0*wcomb[32+f0] + h1*wcomb[32+f0+1] + h2*wcomb[32+f0+2] + h3*wcomb[32+f0+3];
  #pragma unroll
  for (int off = 4; off; off >>= 1){
    p += __shfl_xor(p, off);
    q += __shfl_xor(q, off);
  }
  if (lane == 0){ s1[wid] = p; s2[wid] = q; }
}

__global__ void edge_score_k(const int* __restrict__ src, const int* __restrict__ dst,
                             const float* __restrict__ s1, const float* __restrict__ s2,
                             const float* __restrict__ ccomb, float* __restrict__ out){
  int e = blockIdx.x*blockDim.x + threadIdx.x;
  if (e >= N_EDGES) return;
  out[e] = s1[src[e]] + s2[dst[e]] + ccomb[0];
}

extern "C" void kernel_launch(void* const* d_in, const int* in_sizes, int n_in,
                              void* d_out, int out_size, void* d_ws, size_t ws_size,
                              hipStream_t stream){
  const float* x      = (const float*)d_in[0];
  const float* W      = (const float*)d_in[1];
  const float* attn_l = (const float*)d_in[2];
  const float* attn_r = (const float*)d_in[3];
  const float* bias   = (const float*)d_in[4];
  const float* W1     = (const float*)d_in[5];
  const float* b1     = (const float*)d_in[6];
  const float* W2     = (const float*)d_in[7];
  const float* b2     = (const float*)d_in[8];
  const int*   src    = (const int*)d_in[9];
  const int*   dst    = (const int*)d_in[10];
  float* out = (float*)d_out;

  float* ws = (float*)d_ws;
  size_t off = 0;
  __half* feat16 = (__half*)(ws + off); off += (size_t)N_NODES*HO/2;
  float*  el     = ws + off; off += (size_t)N_NODES*HEADS;
  float*  er     = ws + off; off += (size_t)N_NODES*HEADS;
  float*  s1     = ws + off; off += N_NODES;
  float*  s2     = ws + off; off += N_NODES;
  float*  wcomb  = ws + off; off += 64;
  float*  ccomb  = ws + off; off += 64;
  int*    deg    = (int*)(ws + off); off += N_NODES;
  int*    cursor = (int*)(ws + off); off += N_NODES;
  int*    exsc   = (int*)(ws + off); off += N_NODES;
  int*    rowptr = (int*)(ws + off); off += N_NODES + 1;
  int*    tsum   = (int*)(ws + off); off += NB_SCAN;
  int*    toff   = (int*)(ws + off); off += NB_SCAN + 2;
  int*    srcs   = (int*)(ws + off); off += N_EDGES;

  init_ws_k<<<(N_NODES + 255)/256, 256, 0, stream>>>(deg, cursor);
  feat_k<<<(N_NODES + 63)/64, 256, 0, stream>>>(x, W, attn_l, attn_r, feat16, el, er);
  fold_w_k<<<1, 128, 0, stream>>>(W1, b1, W2, b2, wcomb, ccomb);
  hist_k<<<(N_EDGES + 255)/256, 256, 0, stream>>>(dst, deg);
  scan1_k<<<NB_SCAN, 256, 0, stream>>>(deg, exsc, tsum);
  scan2_k<<<1, 64, 0, stream>>>(tsum, toff);
  scan3_k<<<NB_SCAN, 256, 0, stream>>>(exsc, toff, rowptr);
  scatter_k<<<(N_EDGES + 255)/256, 256, 0, stream>>>(src, dst, rowptr, cursor, srcs);
  node_agg_k<<<((size_t)N_NODES*64 + 255)/256, 256, 0, stream>>>(rowptr, srcs, el, er, feat16, bias, wcomb, s1, s2);
  edge_score_k<<<(N_EDGES + 255)/256, 256, 0, stream>>>(src, dst, s1, s2, ccomb, out);
}